// Round 3
// baseline (27.516 us; speedup 1.0000x reference)
//
#include <hip/hip_runtime.h>
#include <hip/hip_bf16.h>

// out[n] = exp(-0.5 * (x[n]-mu)^T cov (x[n]-mu)), x:[N,2] f32, mu:[2], cov:[2,2]
// Streaming, memory-bound. 8 points/thread: 4x16B nt loads, 2x16B nt stores.

typedef float f32x4 __attribute__((ext_vector_type(4)));

__device__ __forceinline__ float quad_exp(float dx, float dy,
                                          float c00, float cxy, float c11) {
    return __expf(-0.5f * (c00 * dx * dx + cxy * dx * dy + c11 * dy * dy));
}

__global__ __launch_bounds__(256) void gauss_pdf_kernel(
    const f32x4* __restrict__ x4,
    const float* __restrict__ mu,
    const float* __restrict__ cov,
    f32x4* __restrict__ out4,
    int n8) {   // n8 = N/8 work items
    const float mx  = mu[0];
    const float my  = mu[1];
    const float c00 = cov[0];
    const float cxy = cov[1] + cov[2];
    const float c11 = cov[3];

    int i = blockIdx.x * blockDim.x + threadIdx.x;
    if (i >= n8) return;

    // 8 points per thread: x4[4i..4i+3] = 8 (x,y) pairs; out4[2i..2i+1].
    f32x4 a = __builtin_nontemporal_load(&x4[4 * i]);
    f32x4 b = __builtin_nontemporal_load(&x4[4 * i + 1]);
    f32x4 c = __builtin_nontemporal_load(&x4[4 * i + 2]);
    f32x4 d = __builtin_nontemporal_load(&x4[4 * i + 3]);

    f32x4 r0, r1;
    r0.x = quad_exp(a.x - mx, a.y - my, c00, cxy, c11);
    r0.y = quad_exp(a.z - mx, a.w - my, c00, cxy, c11);
    r0.z = quad_exp(b.x - mx, b.y - my, c00, cxy, c11);
    r0.w = quad_exp(b.z - mx, b.w - my, c00, cxy, c11);
    r1.x = quad_exp(c.x - mx, c.y - my, c00, cxy, c11);
    r1.y = quad_exp(c.z - mx, c.w - my, c00, cxy, c11);
    r1.z = quad_exp(d.x - mx, d.y - my, c00, cxy, c11);
    r1.w = quad_exp(d.z - mx, d.w - my, c00, cxy, c11);

    __builtin_nontemporal_store(r0, &out4[2 * i]);
    __builtin_nontemporal_store(r1, &out4[2 * i + 1]);
}

// Scalar tail for N % 8 != 0 (not hit at N=8388608, kept for correctness).
__global__ void gauss_pdf_tail(const float* __restrict__ x,
                               const float* __restrict__ mu,
                               const float* __restrict__ cov,
                               float* __restrict__ out,
                               int start, int n) {
    const float mx  = mu[0];
    const float my  = mu[1];
    const float c00 = cov[0];
    const float cxy = cov[1] + cov[2];
    const float c11 = cov[3];
    for (int i = start + threadIdx.x; i < n; i += blockDim.x) {
        float dx = x[2 * i] - mx, dy = x[2 * i + 1] - my;
        out[i] = __expf(-0.5f * (c00 * dx * dx + cxy * dx * dy + c11 * dy * dy));
    }
}

extern "C" void kernel_launch(void* const* d_in, const int* in_sizes, int n_in,
                              void* d_out, int out_size, void* d_ws, size_t ws_size,
                              hipStream_t stream) {
    const float* x   = (const float*)d_in[0];   // [N,2]
    const float* mu  = (const float*)d_in[1];   // [2]
    const float* cov = (const float*)d_in[2];   // [2,2]
    float* out       = (float*)d_out;           // [N]

    const int n  = out_size;   // N points
    const int n8 = n / 8;

    const int block = 256;
    const int grid  = (n8 + block - 1) / block;   // exact fit

    if (n8 > 0) {
        gauss_pdf_kernel<<<grid, block, 0, stream>>>(
            (const f32x4*)x, mu, cov, (f32x4*)out, n8);
    }

    int rem = n - n8 * 8;
    if (rem > 0) {
        gauss_pdf_tail<<<1, 64, 0, stream>>>(x, mu, cov, out, n8 * 8, n);
    }
}

// Round 4
// 21.169 us; speedup vs baseline: 1.2998x; 1.2998x over previous
//
#include <hip/hip_runtime.h>
#include <hip/hip_bf16.h>

// out[n] = exp(-0.5 * (x[n]-mu)^T cov (x[n]-mu)), x:[N,2] f32, mu:[2], cov:[2,2]
// Streaming, memory-bound. Max-TLP variant: 2 points/thread,
// one 16B load + one 8B nt store per thread, 16384 blocks.

typedef float f32x4 __attribute__((ext_vector_type(4)));
typedef float f32x2 __attribute__((ext_vector_type(2)));

__global__ __launch_bounds__(256) void gauss_pdf_kernel(
    const f32x4* __restrict__ x4,
    const float* __restrict__ mu,
    const float* __restrict__ cov,
    f32x2* __restrict__ out2,
    int n2) {   // n2 = N/2 work items
    const float mx  = mu[0];
    const float my  = mu[1];
    const float c00 = cov[0];
    const float cxy = cov[1] + cov[2];
    const float c11 = cov[3];

    int i = blockIdx.x * blockDim.x + threadIdx.x;
    if (i >= n2) return;

    // 2 points per thread: x4[i] = {x0,y0,x1,y1}
    f32x4 a = x4[i];

    f32x2 r;
    float dx = a.x - mx, dy = a.y - my;
    r.x = __expf(-0.5f * (c00 * dx * dx + cxy * dx * dy + c11 * dy * dy));

    dx = a.z - mx; dy = a.w - my;
    r.y = __expf(-0.5f * (c00 * dx * dx + cxy * dx * dy + c11 * dy * dy));

    __builtin_nontemporal_store(r, &out2[i]);
}

// Scalar tail for N % 2 != 0 (not hit at N=8388608, kept for correctness).
__global__ void gauss_pdf_tail(const float* __restrict__ x,
                               const float* __restrict__ mu,
                               const float* __restrict__ cov,
                               float* __restrict__ out,
                               int start, int n) {
    const float mx  = mu[0];
    const float my  = mu[1];
    const float c00 = cov[0];
    const float cxy = cov[1] + cov[2];
    const float c11 = cov[3];
    for (int i = start + threadIdx.x; i < n; i += blockDim.x) {
        float dx = x[2 * i] - mx, dy = x[2 * i + 1] - my;
        out[i] = __expf(-0.5f * (c00 * dx * dx + cxy * dx * dy + c11 * dy * dy));
    }
}

extern "C" void kernel_launch(void* const* d_in, const int* in_sizes, int n_in,
                              void* d_out, int out_size, void* d_ws, size_t ws_size,
                              hipStream_t stream) {
    const float* x   = (const float*)d_in[0];   // [N,2]
    const float* mu  = (const float*)d_in[1];   // [2]
    const float* cov = (const float*)d_in[2];   // [2,2]
    float* out       = (float*)d_out;           // [N]

    const int n  = out_size;   // N points
    const int n2 = n / 2;

    const int block = 256;
    const int grid  = (n2 + block - 1) / block;   // exact fit, 16384 blocks at N=8.4M

    if (n2 > 0) {
        gauss_pdf_kernel<<<grid, block, 0, stream>>>(
            (const f32x4*)x, mu, cov, (f32x2*)out, n2);
    }

    int rem = n - n2 * 2;
    if (rem > 0) {
        gauss_pdf_tail<<<1, 64, 0, stream>>>(x, mu, cov, out, n2 * 2, n);
    }
}